// Round 1
// baseline (793.677 us; speedup 1.0000x reference)
//
#include <hip/hip_runtime.h>

// TemporalLSTM: x[16384,200,5] fp32 -> LSTM(H=32, torch gate order i,f,g,o)
// -> h_n[16384,32] @ W_fc^T + b_fc -> out[16384,2] fp32.
//
// Design (round 1, fp32 baseline):
//  - One wave (64 lanes) per batch element; 16384 waves total.
//  - Lane l owns gate rows l and l+64 of the 128 gate rows:
//      lanes 0..31 : rows j      (i_j)  and j+64  (g_j)
//      lanes 32..63: rows 32+j   (f_j)  and 96+j  (o_j)
//    -> one __shfl_down(x,32) aligns (f_j,o_j) onto the lane holding (i_j,g_j).
//  - W_hh rows for the lane's 2 gates live in 64 VGPRs (loaded once, reused
//    200 steps). h broadcast via v_readlane -> SGPR operand of v_fmac: zero
//    LDS-pipe traffic (LDS broadcast would be DS-return-BW bound).
//  - sigmoid(x) = rcp(1+exp2(-log2e*x)); tanh via the same path (2 trans ops
//    each, ~1ulp, fine vs 6.1e-3 absmax threshold).

constexpr int kB  = 16384;
constexpr int kT  = 200;
constexpr int kIN = 5;
constexpr int kH  = 32;   // hidden
// 4*kH = 128 gate rows

__device__ __forceinline__ float rcp_fast(float x)  { return __builtin_amdgcn_rcpf(x); }
__device__ __forceinline__ float exp2_fast(float x) { return __builtin_amdgcn_exp2f(x); }

__global__ __launch_bounds__(256) void lstm_fused(
    const float* __restrict__ x,     // [B, T, 5]
    const float* __restrict__ W_ih,  // [128, 5]
    const float* __restrict__ W_hh,  // [128, 32]
    const float* __restrict__ b_ih,  // [128]
    const float* __restrict__ b_hh,  // [128]
    const float* __restrict__ W_fc,  // [2, 32]
    const float* __restrict__ b_fc,  // [2]
    float* __restrict__ out)         // [B, 2]
{
    const int tid  = blockIdx.x * blockDim.x + threadIdx.x;
    const int wave = tid >> 6;            // batch index, exact: grid covers kB waves
    const int lane = threadIdx.x & 63;
    const int r0   = lane;                // gate row (i|f half)
    const int r1   = lane + 64;           // gate row (g|o half)
    const bool low = (lane < 32);

    // ---- weights resident in VGPRs (reused 200 steps) ----
    float w0[kH], w1[kH];
#pragma unroll
    for (int k = 0; k < kH; ++k) {
        w0[k] = W_hh[r0 * kH + k];
        w1[k] = W_hh[r1 * kH + k];
    }
    float wi0[kIN], wi1[kIN];
#pragma unroll
    for (int i = 0; i < kIN; ++i) {
        wi0[i] = W_ih[r0 * kIN + i];
        wi1[i] = W_ih[r1 * kIN + i];
    }
    const float bias0 = b_ih[r0] + b_hh[r0];
    const float bias1 = b_ih[r1] + b_hh[r1];

    const float* xb = x + (size_t)wave * (kT * kIN);

    const float NLOG2E = -1.4426950408889634f;  // -log2(e)

    // state: lane j (<32) holds h_j, c_j; high lanes pinned to 0
    float h = 0.0f, c = 0.0f;

    for (int t = 0; t < kT; ++t) {
        // x[t] broadcast: all lanes load the same 5 floats (one L1 line,
        // adjacent t reuses the line)
        float xt[kIN];
#pragma unroll
        for (int i = 0; i < kIN; ++i) xt[i] = xb[t * kIN + i];

        float a0 = bias0, a1 = bias1;
#pragma unroll
        for (int i = 0; i < kIN; ++i) {
            a0 = fmaf(xt[i], wi0[i], a0);
            a1 = fmaf(xt[i], wi1[i], a1);
        }

        // recurrent part: h_k broadcast via readlane (SGPR), 2 fma per k
#pragma unroll
        for (int k = 0; k < kH; ++k) {
            float hk = __uint_as_float(
                __builtin_amdgcn_readlane(__float_as_uint(h), k));
            a0 = fmaf(hk, w0[k], a0);
            a1 = fmaf(hk, w1[k], a1);
        }

        // a0: i (low) / f (high) -> sigmoid for all lanes
        float s0 = rcp_fast(1.0f + exp2_fast(NLOG2E * a0));
        // a1: g (low, tanh) / o (high, sigmoid); tanh(y) = 2*sigmoid(2y)-1
        float z  = low ? (a1 + a1) : a1;
        float sz = rcp_fast(1.0f + exp2_fast(NLOG2E * z));
        float s1 = low ? (sz + sz - 1.0f) : sz;

        // bring f_j, o_j (high lanes) down to the (i_j,g_j) lanes
        float fj = __shfl_down(s0, 32);
        float oj = __shfl_down(s1, 32);

        float cn = fmaf(fj, c, s0 * s1);        // c = f*c + i*g
        float th = 2.0f * rcp_fast(1.0f + exp2_fast(2.0f * NLOG2E * cn)) - 1.0f;
        float hn = oj * th;                      // h = o * tanh(c)

        c = low ? cn : 0.0f;                     // keep high half clean so
        h = low ? hn : 0.0f;                     // readlane k<32 is always valid
    }

    // ---- epilogue: out[b][o] = sum_j h_j * W_fc[o][j] + b_fc[o] ----
    const int jj = lane & 31;                    // in-bounds index for all lanes
    float wfc0 = W_fc[jj];
    float wfc1 = W_fc[kH + jj];
    if (!low) { wfc0 = 0.0f; wfc1 = 0.0f; }
    float p0 = h * wfc0;
    float p1 = h * wfc1;
#pragma unroll
    for (int off = 32; off >= 1; off >>= 1) {
        p0 += __shfl_xor(p0, off);
        p1 += __shfl_xor(p1, off);
    }
    if (lane == 0) {
        out[2 * wave + 0] = p0 + b_fc[0];
        out[2 * wave + 1] = p1 + b_fc[1];
    }
}

extern "C" void kernel_launch(void* const* d_in, const int* in_sizes, int n_in,
                              void* d_out, int out_size, void* d_ws, size_t ws_size,
                              hipStream_t stream) {
    const float* x    = (const float*)d_in[0];
    const float* W_ih = (const float*)d_in[1];
    const float* W_hh = (const float*)d_in[2];
    const float* b_ih = (const float*)d_in[3];
    const float* b_hh = (const float*)d_in[4];
    const float* W_fc = (const float*)d_in[5];
    const float* b_fc = (const float*)d_in[6];
    float* out = (float*)d_out;

    // one wave per batch element: 16384 waves = 4096 blocks x 256 threads
    dim3 grid(kB / 4), block(256);
    hipLaunchKernelGGL(lstm_fused, grid, block, 0, stream,
                       x, W_ih, W_hh, b_ih, b_hh, W_fc, b_fc, out);
}

// Round 2
// 287.264 us; speedup vs baseline: 2.7629x; 2.7629x over previous
//
#include <hip/hip_runtime.h>

// TemporalLSTM via split-bf16 MFMA (gfx950).
// x[16384,200,5] fp32 -> LSTM(H=32, gates i,f,g,o) -> h_200 @ W_fc^T + b_fc -> out[16384,2]
//
// One wave (64 thr) per 16 batches => 1024 blocks. Per step, gates[16 batch x 128] via
// mfma_f32_16x16x32_bf16, 8 N-tiles x 4 mfma:
//   tile acc = mfma(x_frag, wih_combo) ; += A_hi*Whh_hi ; += A_hi*Whh_lo ; += A_lo*Whh_hi
// Split-bf16 (hi + residual lo) makes the GEMM fp32-accurate (dropped lo*lo ~ 2^-18).
// wih_combo packs x-proj AND bias into one mfma:
//   k 0..4  : A=x_hi[i],  B=Wih_hi[r][i]
//   k 5..9  : A=x_lo[i],  B=Wih_hi[r][i]
//   k 10..14: A=x_hi[i],  B=Wih_lo[r][i]
//   k 15    : A=1.0,      B=bias_hi[r]      (bias = b_ih + b_hh)
//   k 16    : A=1.0,      B=bias_lo[r]      (quad-2 lanes: constant frag, no LDS read)
// C/D layout (m89): row m=(lane>>4)*4+reg, col n=lane&15. Tiles: i=0,1 f=2,3 g=4,5 o=6,7
// => i_j,f_j,g_j,o_j of one (batch,j) sit in the SAME lane: pointwise update is local.
// h round-trip: packed (hi<<16|lo) u32 in LDS [m][k], stride 36; read back as A-frags
// (A layout m120: m=lane&15, k=(lane>>4)*8+j) with 2x b128 + v_perm unpack.

typedef __bf16 bf16x8 __attribute__((ext_vector_type(8)));
typedef float  f32x4  __attribute__((ext_vector_type(4)));
typedef unsigned int u32;

constexpr int kT = 200, kIN = 5, kH = 32;
constexpr int CT   = 40;   // timesteps of x staged in LDS per phase (200 = 5*40)
constexpr int HSTR = 36;   // hbuf row stride (u32): (m+?) padding -> benign conflicts

union FragU {
    bf16x8 v;
    unsigned short s[8];
    u32 u[4];
};

__device__ __forceinline__ u32 bf16_rne(float f) {
    u32 u = __float_as_uint(f);
    return (u + 0x7FFFu + ((u >> 16) & 1u)) >> 16;   // round-to-nearest-even bf16 bits
}
__device__ __forceinline__ float bf16f(u32 bits) { return __uint_as_float(bits << 16); }
__device__ __forceinline__ void split2(float x, u32& hi, u32& lo) {
    hi = bf16_rne(x);
    lo = bf16_rne(x - bf16f(hi));                    // residual, |lo| <= 2^-9 |x|
}

__device__ __forceinline__ float sigm(float z) {
    return __builtin_amdgcn_rcpf(1.0f + __builtin_amdgcn_exp2f(-1.4426950408889634f * z));
}
__device__ __forceinline__ float tanhv(float z) {
    return fmaf(2.0f,
        __builtin_amdgcn_rcpf(1.0f + __builtin_amdgcn_exp2f(-2.8853900817779268f * z)),
        -1.0f);
}

__global__ __launch_bounds__(64, 1) void lstm_mfma(
    const float* __restrict__ x,     // [B,200,5]
    const float* __restrict__ W_ih,  // [128,5]
    const float* __restrict__ W_hh,  // [128,32]
    const float* __restrict__ b_ih,  // [128]
    const float* __restrict__ b_hh,  // [128]
    const float* __restrict__ W_fc,  // [2,32]
    const float* __restrict__ b_fc,  // [2]
    float* __restrict__ out)         // [B,2]
{
    __shared__ uint4 xbuf[CT][33];        // [tc][m*2+q] A-frags for x (q=0,1)
    __shared__ u32   hbuf[16 * HSTR];     // packed h (hi<<16|lo) at [m][k]

    const int lane = threadIdx.x;         // 0..63
    const int n16  = lane & 15;
    const int q    = lane >> 4;
    const int b0   = blockIdx.x * 16;

    // ---- weight B-frags, resident in VGPRs (B[k][n]: lane holds n=lane&15, k=q*8+j) ----
    bf16x8 whhh[8], whhl[8], wihf[8];
#pragma unroll
    for (int t = 0; t < 8; ++t) {
        const int r = t * 16 + n16;       // gate row 0..127
        FragU H, L;
#pragma unroll
        for (int j = 0; j < 8; ++j) {
            u32 hi, lo;
            split2(W_hh[r * kH + q * 8 + j], hi, lo);
            H.s[j] = (unsigned short)hi;
            L.s[j] = (unsigned short)lo;
        }
        whhh[t] = H.v;
        whhl[t] = L.v;

        FragU F;
        F.u[0] = F.u[1] = F.u[2] = F.u[3] = 0u;
        float wr[5];
#pragma unroll
        for (int i = 0; i < 5; ++i) wr[i] = W_ih[r * kIN + i];
        u32 bh, bl;
        split2(b_ih[r] + b_hh[r], bh, bl);
        if (q == 0) {
#pragma unroll
            for (int i = 0; i < 5; ++i) F.s[i] = (unsigned short)bf16_rne(wr[i]);       // k0..4
#pragma unroll
            for (int i = 5; i < 8; ++i) F.s[i] = (unsigned short)bf16_rne(wr[i - 5]);   // k5..7
        } else if (q == 1) {
            F.s[0] = (unsigned short)bf16_rne(wr[3]);                                   // k8
            F.s[1] = (unsigned short)bf16_rne(wr[4]);                                   // k9
#pragma unroll
            for (int i = 0; i < 5; ++i) {                                               // k10..14
                u32 hi, lo; split2(wr[i], hi, lo);
                F.s[2 + i] = (unsigned short)lo;
            }
            F.s[7] = (unsigned short)bh;                                                // k15
        } else if (q == 2) {
            F.s[0] = (unsigned short)bl;                                                // k16
        }
        wihf[t] = F.v;
    }

    // ---- zero h (t=0 state) ----
#pragma unroll
    for (int i = 0; i < 9; ++i) hbuf[lane * 9 + i] = 0u;
    __syncthreads();

    float cst[2][4] = {{0.f, 0.f, 0.f, 0.f}, {0.f, 0.f, 0.f, 0.f}};
    const uint4* hb4 = (const uint4*)hbuf;

    for (int phase = 0; phase < kT / CT; ++phase) {
        // ---- stage CT steps of x as ready-made A-frags (lane -> m=lane>>2, p=lane&3) ----
        {
            const int mm = lane >> 2, pp = lane & 3;
            const float* xrow = x + (size_t)(b0 + mm) * (kT * kIN)
                                  + (size_t)(phase * CT + pp * (CT / 4)) * kIN;
            float xv[(CT / 4) * kIN];                       // 50 floats, 8B-aligned runs
            const float2* xr2 = (const float2*)xrow;
#pragma unroll
            for (int i = 0; i < (CT / 4) * kIN / 2; ++i) {
                float2 v = xr2[i];
                xv[2 * i] = v.x; xv[2 * i + 1] = v.y;
            }
#pragma unroll
            for (int s5 = 0; s5 < CT / 4; ++s5) {
                u32 xh[5], xl[5];
#pragma unroll
                for (int i = 0; i < 5; ++i) split2(xv[s5 * 5 + i], xh[i], xl[i]);
                uint4 f0 = make_uint4(xh[0] | (xh[1] << 16),
                                      xh[2] | (xh[3] << 16),
                                      xh[4] | (xl[0] << 16),
                                      xl[1] | (xl[2] << 16));
                uint4 f1 = make_uint4(xl[3] | (xl[4] << 16),
                                      xh[0] | (xh[1] << 16),
                                      xh[2] | (xh[3] << 16),
                                      xh[4] | (0x3F80u << 16));   // k15: A = 1.0
                const int tc = pp * (CT / 4) + s5;
                xbuf[tc][mm * 2 + 0] = f0;
                xbuf[tc][mm * 2 + 1] = f1;
            }
        }
        __syncthreads();

        for (int tc = 0; tc < CT; ++tc) {
            // x A-frag: quads 0,1 from LDS; quad 2 = [1,0,...] (bias_lo row); quad 3 = 0
            FragU xf;
            if (q < 2) {
                *(uint4*)&xf = xbuf[tc][n16 * 2 + q];
            } else if (q == 2) {
                xf.u[0] = 0x3F80u; xf.u[1] = 0u; xf.u[2] = 0u; xf.u[3] = 0u;
            } else {
                xf.u[0] = 0u; xf.u[1] = 0u; xf.u[2] = 0u; xf.u[3] = 0u;
            }

            // h A-frags (hi & lo) from packed LDS
            uint4 w0 = hb4[n16 * 9 + q * 2];
            uint4 w1 = hb4[n16 * 9 + q * 2 + 1];
            FragU AH, AL;
            AH.u[0] = __builtin_amdgcn_perm(w0.y, w0.x, 0x07060302u);
            AH.u[1] = __builtin_amdgcn_perm(w0.w, w0.z, 0x07060302u);
            AH.u[2] = __builtin_amdgcn_perm(w1.y, w1.x, 0x07060302u);
            AH.u[3] = __builtin_amdgcn_perm(w1.w, w1.z, 0x07060302u);
            AL.u[0] = __builtin_amdgcn_perm(w0.y, w0.x, 0x05040100u);
            AL.u[1] = __builtin_amdgcn_perm(w0.w, w0.z, 0x05040100u);
            AL.u[2] = __builtin_amdgcn_perm(w1.y, w1.x, 0x05040100u);
            AL.u[3] = __builtin_amdgcn_perm(w1.w, w1.z, 0x05040100u);

            // gates = x@Wih^T + bias + h@Whh^T   (split-bf16, fp32 accumulate)
            f32x4 acc[8];
#pragma unroll
            for (int t = 0; t < 8; ++t) {
                f32x4 a = {0.f, 0.f, 0.f, 0.f};
                a = __builtin_amdgcn_mfma_f32_16x16x32_bf16(xf.v,  wihf[t], a, 0, 0, 0);
                a = __builtin_amdgcn_mfma_f32_16x16x32_bf16(AH.v, whhh[t], a, 0, 0, 0);
                a = __builtin_amdgcn_mfma_f32_16x16x32_bf16(AH.v, whhl[t], a, 0, 0, 0);
                a = __builtin_amdgcn_mfma_f32_16x16x32_bf16(AL.v, whhh[t], a, 0, 0, 0);
                acc[t] = a;
            }

            // pointwise LSTM update; lane owns (m = q*4+r, j = n16 + 16*jg)
#pragma unroll
            for (int jg = 0; jg < 2; ++jg) {
#pragma unroll
                for (int r = 0; r < 4; ++r) {
                    float iv = sigm (acc[0 + jg][r]);
                    float fv = sigm (acc[2 + jg][r]);
                    float gv = tanhv(acc[4 + jg][r]);
                    float ov = sigm (acc[6 + jg][r]);
                    float cn = fmaf(fv, cst[jg][r], iv * gv);
                    cst[jg][r] = cn;
                    float hn = ov * tanhv(cn);
                    u32 hh, hl;
                    split2(hn, hh, hl);
                    hbuf[(q * 4 + r) * HSTR + n16 + 16 * jg] = (hh << 16) | hl;
                }
            }
            __syncthreads();
        }
    }

    // ---- epilogue: out[b][o] = h . W_fc[o] + b_fc[o]; h rebuilt from hi+lo (~fp32) ----
    if (lane < 32) {
        const int m = lane >> 1, o = lane & 1;
        float s = b_fc[o];
#pragma unroll
        for (int j = 0; j < kH; ++j) {
            u32 pk = hbuf[m * HSTR + j];
            float hv = bf16f(pk >> 16) + bf16f(pk & 0xFFFFu);
            s = fmaf(hv, W_fc[o * kH + j], s);
        }
        out[(size_t)(b0 + m) * 2 + o] = s;
    }
}

extern "C" void kernel_launch(void* const* d_in, const int* in_sizes, int n_in,
                              void* d_out, int out_size, void* d_ws, size_t ws_size,
                              hipStream_t stream) {
    const float* x    = (const float*)d_in[0];
    const float* W_ih = (const float*)d_in[1];
    const float* W_hh = (const float*)d_in[2];
    const float* b_ih = (const float*)d_in[3];
    const float* b_hh = (const float*)d_in[4];
    const float* W_fc = (const float*)d_in[5];
    const float* b_fc = (const float*)d_in[6];
    float* out = (float*)d_out;

    // 16384 batches / 16 per wave = 1024 blocks of one wave each
    hipLaunchKernelGGL(lstm_mfma, dim3(1024), dim3(64), 0, stream,
                       x, W_ih, W_hh, b_ih, b_hh, W_fc, b_fc, out);
}

// Round 3
// 283.659 us; speedup vs baseline: 2.7980x; 1.0127x over previous
//
#include <hip/hip_runtime.h>

// TemporalLSTM via split-bf16 MFMA, round 3 (gfx950).
// x[16384,200,5] fp32 -> LSTM(H=32, gates i,f,g,o) -> h_200 @ W_fc^T + b_fc -> out[16384,2]
//
// Round-3 structure:
//  - 1024 blocks x 128 threads (2 waves). Block owns 16 batches (one M=16 mfma tile).
//  - Gate tiles split by j-half across the 2 waves: wave w computes tiles
//    {i,f,g,o} for gate columns j in [16w, 16w+16)  => 16 mfma per wave per step.
//    2048 waves total = 2 waves/SIMD (round 2 had 1/SIMD, VALUBusy 64%).
//  - h stored as SEPARATE hi/lo bf16 LDS arrays (stride 40 shorts, 16B-aligned):
//    A-frag read = one ds_read_b128 each (no v_perm unpack); write = ds_write_b16.
//    Ping-pong h buffers => single __syncthreads per step (write->read hazard only).
//  - Split-bf16 (hi + residual lo) GEMM, fp32 accumulate: dropped lo*lo ~ 2^-18.
//    x-proj + bias packed in one K<=17 mfma (same verified frag layout as round 2):
//      k0..4: A=x_hi,B=Wih_hi | k5..9: A=x_lo,B=Wih_hi | k10..14: A=x_hi,B=Wih_lo
//      k15: A=1,B=bias_hi | k16 (quad2): A=1,B=bias_lo
//  - C/D layout: m=q*4+reg, n=lane&15 => i,f,g,o of one (batch,j) in the SAME lane.

typedef __bf16 bf16x8 __attribute__((ext_vector_type(8)));
typedef float  f32x4  __attribute__((ext_vector_type(4)));
typedef unsigned int u32;

constexpr int kT = 200, kIN = 5, kH = 32;
constexpr int CT   = 40;   // timesteps of x staged per phase (200 = 5*40)
constexpr int HSTR = 40;   // bf16 elements per h row: 80 B, keeps b128 reads 16B-aligned

union FragU { bf16x8 v; __bf16 b[8]; unsigned short s[8]; u32 u[4]; uint4 q4; };

__device__ __forceinline__ unsigned short bfbits(__bf16 b) {
    union { __bf16 b; unsigned short s; } u; u.b = b; return u.s;
}
__device__ __forceinline__ void split2(float x, __bf16& hi, __bf16& lo) {
    hi = (__bf16)x;                 // RNE cvt (gfx950 native)
    lo = (__bf16)(x - (float)hi);   // residual, |lo| <= 2^-9 |x|
}
__device__ __forceinline__ float sigm(float z) {
    return __builtin_amdgcn_rcpf(1.0f + __builtin_amdgcn_exp2f(-1.4426950408889634f * z));
}
__device__ __forceinline__ float tanhv(float z) {
    return fmaf(2.0f,
        __builtin_amdgcn_rcpf(1.0f + __builtin_amdgcn_exp2f(-2.8853900817779268f * z)),
        -1.0f);
}

__global__ __launch_bounds__(128) void lstm_mfma2(
    const float* __restrict__ x,     // [B,200,5]
    const float* __restrict__ W_ih,  // [128,5]
    const float* __restrict__ W_hh,  // [128,32]
    const float* __restrict__ b_ih,  // [128]
    const float* __restrict__ b_hh,  // [128]
    const float* __restrict__ W_fc,  // [2,32]
    const float* __restrict__ b_fc,  // [2]
    float* __restrict__ out)         // [B,2]
{
    __shared__ uint4 xbuf[CT][33];                       // x A-frags per step
    __shared__ __align__(16) __bf16 hbh[2][16 * HSTR];   // h hi, ping-pong
    __shared__ __align__(16) __bf16 hbl[2][16 * HSTR];   // h lo, ping-pong

    const int tid  = threadIdx.x;
    const int wv   = tid >> 6;        // wave: j-half 0 or 1
    const int lane = tid & 63;
    const int n16  = lane & 15;
    const int q    = lane >> 4;
    const int b0   = blockIdx.x * 16;

    // ---- weight B-frags resident in VGPRs: this wave's 4 tiles {i,f,g,o} ----
    bf16x8 whhh[4], whhl[4], wihf[4];
#pragma unroll
    for (int g = 0; g < 4; ++g) {
        const int t = 2 * g + wv;          // tile index 0..7
        const int r = t * 16 + n16;        // gate row 0..127
        FragU H, L;
#pragma unroll
        for (int j = 0; j < 8; ++j)
            split2(W_hh[r * kH + q * 8 + j], H.b[j], L.b[j]);
        whhh[g] = H.v; whhl[g] = L.v;

        float wr[5];
#pragma unroll
        for (int i = 0; i < 5; ++i) wr[i] = W_ih[r * kIN + i];
        __bf16 bh, bl;
        split2(b_ih[r] + b_hh[r], bh, bl);

        FragU F;
        F.u[0] = F.u[1] = F.u[2] = F.u[3] = 0u;
        if (q == 0) {
#pragma unroll
            for (int i = 0; i < 5; ++i) F.b[i] = (__bf16)wr[i];        // k0..4
#pragma unroll
            for (int i = 0; i < 3; ++i) F.b[5 + i] = (__bf16)wr[i];    // k5..7
        } else if (q == 1) {
            F.b[0] = (__bf16)wr[3];                                    // k8
            F.b[1] = (__bf16)wr[4];                                    // k9
#pragma unroll
            for (int i = 0; i < 5; ++i) {                              // k10..14
                __bf16 hb, lb; split2(wr[i], hb, lb);
                F.b[2 + i] = lb;
            }
            F.b[7] = bh;                                               // k15
        } else if (q == 2) {
            F.b[0] = bl;                                               // k16
        }
        wihf[g] = F.v;
    }

    // ---- zero parity-0 h (t=0 state) ----
    {
        u32* z0 = (u32*)&hbh[0][0];
        u32* z1 = (u32*)&hbl[0][0];
        for (int i = tid; i < (16 * HSTR) / 2; i += 128) { z0[i] = 0u; z1[i] = 0u; }
    }

    float cst[4] = {0.f, 0.f, 0.f, 0.f};

    const int hro = n16 * HSTR + q * 8;                  // A-frag read offset (m=n16, k=q*8..)
    const int hwo = (q * 4) * HSTR + n16 + 16 * wv;      // h write offset (+ r*HSTR)

    auto step = [&](int tc, const __bf16* sh, const __bf16* sl,
                    __bf16* dh, __bf16* dl) {
        FragU xf;
        if (q < 2) {
            xf.q4 = xbuf[tc][n16 * 2 + q];
        } else if (q == 2) {
            xf.u[0] = 0x3F80u; xf.u[1] = 0u; xf.u[2] = 0u; xf.u[3] = 0u;  // k16: A=1
        } else {
            xf.u[0] = 0u; xf.u[1] = 0u; xf.u[2] = 0u; xf.u[3] = 0u;
        }

        bf16x8 AH = *(const bf16x8*)(sh + hro);
        bf16x8 AL = *(const bf16x8*)(sl + hro);

        f32x4 acc[4];
#pragma unroll
        for (int g = 0; g < 4; ++g) {
            f32x4 a = {0.f, 0.f, 0.f, 0.f};
            a = __builtin_amdgcn_mfma_f32_16x16x32_bf16(xf.v, wihf[g], a, 0, 0, 0);
            a = __builtin_amdgcn_mfma_f32_16x16x32_bf16(AH,   whhh[g], a, 0, 0, 0);
            a = __builtin_amdgcn_mfma_f32_16x16x32_bf16(AH,   whhl[g], a, 0, 0, 0);
            a = __builtin_amdgcn_mfma_f32_16x16x32_bf16(AL,   whhh[g], a, 0, 0, 0);
            acc[g] = a;
        }

        // pointwise: lane owns (m = q*4+r, j = n16 + 16*wv)
#pragma unroll
        for (int r = 0; r < 4; ++r) {
            float iv = sigm (acc[0][r]);
            float fv = sigm (acc[1][r]);
            float gv = tanhv(acc[2][r]);
            float ov = sigm (acc[3][r]);
            float cn = fmaf(fv, cst[r], iv * gv);
            cst[r] = cn;
            float hn = ov * tanhv(cn);
            __bf16 hh, hl;
            split2(hn, hh, hl);
            dh[hwo + r * HSTR] = hh;
            dl[hwo + r * HSTR] = hl;
        }
        __syncthreads();   // one barrier per step: writes(t+1) -> reads(t+1)
    };

    for (int phase = 0; phase < kT / CT; ++phase) {
        // ---- stage CT steps of x as ready-made A-frags (128 threads) ----
        {
            const int mm = tid >> 3, pp = tid & 7;       // batch row, 5-step chunk
            const float* xrow = x + (size_t)(b0 + mm) * (kT * kIN)
                                  + (size_t)(phase * CT + pp * 5) * kIN;
            float xv[25];
#pragma unroll
            for (int i = 0; i < 25; ++i) xv[i] = xrow[i];
#pragma unroll
            for (int s5 = 0; s5 < 5; ++s5) {
                u32 xh[5], xl[5];
#pragma unroll
                for (int i = 0; i < 5; ++i) {
                    __bf16 hb, lb; split2(xv[s5 * 5 + i], hb, lb);
                    xh[i] = bfbits(hb); xl[i] = bfbits(lb);
                }
                uint4 f0 = make_uint4(xh[0] | (xh[1] << 16),
                                      xh[2] | (xh[3] << 16),
                                      xh[4] | (xl[0] << 16),
                                      xl[1] | (xl[2] << 16));
                uint4 f1 = make_uint4(xl[3] | (xl[4] << 16),
                                      xh[0] | (xh[1] << 16),
                                      xh[2] | (xh[3] << 16),
                                      xh[4] | (0x3F80u << 16));   // k15: A = 1.0
                const int tc = pp * 5 + s5;
                xbuf[tc][mm * 2 + 0] = f0;
                xbuf[tc][mm * 2 + 1] = f1;
            }
        }
        __syncthreads();   // covers zero-init (phase 0) and xbuf staging

#pragma unroll 1
        for (int tc = 0; tc < CT; tc += 2) {
            step(tc,     hbh[0], hbl[0], hbh[1], hbl[1]);
            step(tc + 1, hbh[1], hbl[1], hbh[0], hbl[0]);
        }
    }

    // ---- epilogue: final h is in parity 0 (200 even). out = h.W_fc + b_fc ----
    if (tid < 32) {
        const int m = tid >> 1, o = tid & 1;
        float s = b_fc[o];
#pragma unroll
        for (int j = 0; j < kH; ++j) {
            float hv = (float)hbh[0][m * HSTR + j] + (float)hbl[0][m * HSTR + j];
            s = fmaf(hv, W_fc[o * kH + j], s);
        }
        out[(size_t)(b0 + m) * 2 + o] = s;
    }
}

extern "C" void kernel_launch(void* const* d_in, const int* in_sizes, int n_in,
                              void* d_out, int out_size, void* d_ws, size_t ws_size,
                              hipStream_t stream) {
    const float* x    = (const float*)d_in[0];
    const float* W_ih = (const float*)d_in[1];
    const float* W_hh = (const float*)d_in[2];
    const float* b_ih = (const float*)d_in[3];
    const float* b_hh = (const float*)d_in[4];
    const float* W_fc = (const float*)d_in[5];
    const float* b_fc = (const float*)d_in[6];
    float* out = (float*)d_out;

    // 16384 batches / 16 per block = 1024 blocks x 128 threads (2 waves)
    hipLaunchKernelGGL(lstm_mfma2, dim3(1024), dim3(128), 0, stream,
                       x, W_ih, W_hh, b_ih, b_hh, W_fc, b_fc, out);
}